// Round 4
// baseline (210.859 us; speedup 1.0000x reference)
//
#include <hip/hip_runtime.h>

// Net_3152505995417: tiny GNN forward (N=116, E=6670, HID=64, EDIM=5).
// R6: 3 dispatches, G ELIMINATED algebraically.
//   S[i,k] = sum_{e inc i} rc[e]*G[e,k]  with  G = relu(ea)@We
//          = (R @ We)[i,k],  R[i,m] = sum_{e inc i} rc[e]*relu(ea[e,m]).
//   -> phase C becomes a coalesced 5-float/edge LDS scatter + 116x5x5 matmul.
//   gp for d2 recomputed from ea (25 fma/edge). G never materialized; the
//   R3 kCDEF 102us pathology (fully-diverged G/eidx gathers) is removed.
//  K1 = X, Y1 (node blocks) + d1 (edge blocks)           [R0-verified code]
//  K2 = x2, dv, Y2                                       [R0-verified code]
//  K3 = R-scatter -> S=R@We -> d2 (own 4 rows) -> x3 -> pool -> head
//       (last-block-finishes; threadfence + agent counter, R3-verified).
// fp-order change vs reference: S double-sum reassociation (~1e-7).

#define NN   116
#define EE   6670
#define HID  64
#define EDIM 5
#define OUTD 4
#define ENC  122
#define EPSF 1e-10f
#define NH   (NN*HID)   // 7424

__device__ __forceinline__ int eid_ij(int i, int j) {
    int a = i < j ? i : j;
    int b = i < j ? j : i;
    return a*NN - ((a*(a+1)) >> 1) + (b - a - 1);   // triu k=1 row-major
}

// K1: node blocks (0..28): X row = enc@W_enc+b_enc (LDS), Y1 row = Xrow@W1.
//     edge blocks (29..55): d1 = ea@p1.
__global__ __launch_bounds__(256) void kA(
    const float* __restrict__ enc, const float* __restrict__ ea,
    const float* __restrict__ W_enc, const float* __restrict__ b_enc,
    const float* __restrict__ p1, const float* __restrict__ W1,
    float* __restrict__ Y1, float* __restrict__ d1)
{
    const int tid = threadIdx.x;
    if (blockIdx.x < 29) {
        __shared__ __align__(16) float sWe[ENC*HID];   // 31232 B
        __shared__ __align__(16) float sW1[HID*HID];   // 16384 B
        __shared__ __align__(16) float sEnc[4*ENC];    //  1952 B
        __shared__ float sX[4*HID];
        {
            const float4* g4 = (const float4*)W_enc; float4* s4 = (float4*)sWe;
            for (int u = tid; u < ENC*HID/4; u += 256) s4[u] = g4[u];
        }
        {
            const float4* g4 = (const float4*)W1; float4* s4 = (float4*)sW1;
            for (int u = tid; u < HID*HID/4; u += 256) s4[u] = g4[u];
        }
        {
            const float4* g4 = (const float4*)(enc + blockIdx.x*4*ENC); // 1952B-aligned
            float4* s4 = (float4*)sEnc;
            for (int u = tid; u < 4*ENC/4; u += 256) s4[u] = g4[u];
        }
        __syncthreads();
        const int w = tid >> 6, h = tid & 63;
        const int i = blockIdx.x*4 + w;
        float acc = b_enc[h];
        const float* er = sEnc + w*ENC;
        #pragma unroll 4
        for (int k = 0; k < ENC; ++k) acc = fmaf(er[k], sWe[k*HID + h], acc);
        sX[w*HID + h] = acc;
        __syncthreads();
        float a2 = 0.f;
        const float* xr = sX + w*HID;
        #pragma unroll 8
        for (int k = 0; k < HID; ++k) a2 = fmaf(xr[k], sW1[k*HID + h], a2);
        Y1[i*HID + h] = a2;
    } else {
        const int u = (blockIdx.x - 29)*256 + tid;
        if (u < EE) {
            const float* r = ea + u*EDIM;
            float a0 = 0.f;
            #pragma unroll
            for (int k = 0; k < EDIM; ++k) a0 = fmaf(r[k], p1[k], a0);
            d1[u] = a0;
        }
    }
}

// K2: x2 row = relu(D1@Y1 + b1); dv[i] = x2row.pe; Y2 row = x2row @ W2.
//     Block 0 also zeroes P and the completion counter for K3.
__global__ __launch_bounds__(256) void kB(
    const float* __restrict__ d1, const float* __restrict__ Y1,
    const float* __restrict__ b1, const float* __restrict__ pe,
    const float* __restrict__ W2,
    float* __restrict__ dv, float* __restrict__ Y2,
    float* __restrict__ P, int* __restrict__ cnt)
{
    __shared__ __align__(16) float sY[NH];   // 29696 B
    __shared__ __align__(16) float sD[EE];   // 26680 B
    __shared__ float sX2[4*HID];
    const int tid = threadIdx.x;
    if (blockIdx.x == 0) {
        if (tid < HID) P[tid] = 0.f;
        if (tid == 0) *cnt = 0;
    }
    {
        const float4* g4 = (const float4*)Y1; float4* s4 = (float4*)sY;
        for (int u = tid; u < NH/4; u += 256) s4[u] = g4[u];
        const float2* g2 = (const float2*)d1; float2* s2 = (float2*)sD;
        for (int u = tid; u < EE/2; u += 256) s2[u] = g2[u];
    }
    __syncthreads();
    const int w = tid >> 6, h = tid & 63;
    const int i = blockIdx.x*4 + w;
    float acc = b1[h];
    #pragma unroll 4
    for (int j = 0; j < NN; ++j) {
        int jj = (j == i) ? (j ^ 1) : j;
        float wgt = (j == i) ? 0.f : sD[eid_ij(i, jj)];
        acc = fmaf(wgt, sY[jj*HID + h], acc);
    }
    float v = fmaxf(acc, 0.f);
    float r = v * pe[h];
    #pragma unroll
    for (int off = 32; off > 0; off >>= 1) r += __shfl_down(r, off, 64);
    if (h == 0) dv[i] = r;
    sX2[w*HID + h] = v;
    __syncthreads();
    float a2 = 0.f;
    const float* xr = sX2 + w*HID;
    #pragma unroll 8
    for (int k = 0; k < HID; ++k) a2 = fmaf(xr[k], W2[k*HID + h], a2);
    Y2[i*HID + h] = a2;
}

// K3: per block (29 blocks, 4 output rows each):
//   stage Y2 + dv; R[116x5] via coalesced edge scatter (rc*relu(ea));
//   S = R@We in LDS; d2 for own 460 edges (gp recomputed from ea);
//   x3 rows; pool -> atomicAdd P; last block computes head.
__global__ __launch_bounds__(256) void kCDEF(
    const int* __restrict__ eidx, const float* __restrict__ ea,
    const float* __restrict__ dvg, const float* __restrict__ Y2,
    const float* __restrict__ We, const float* __restrict__ be,
    const float* __restrict__ p2, const float* __restrict__ b2,
    const float* __restrict__ Wl, const float* __restrict__ bl,
    float* __restrict__ P, int* __restrict__ cnt, float* __restrict__ out)
{
    __shared__ __align__(16) float sY[NH];     // 29696 B
    __shared__ float sRm[NN*EDIM];             // R  [116][5]
    __shared__ float sS [NN*EDIM];             // S  [116][5]
    __shared__ float sDv[NN];
    __shared__ float sD2[4*NN];
    __shared__ float sR[4*HID];
    __shared__ int sLast;
    const int tid = threadIdx.x;
    const int wid = tid >> 6, lane = tid & 63;

    // uniform small weights into registers (scalar loads)
    float Wer[EDIM*EDIM], ber[EDIM], p2r[EDIM];
    #pragma unroll
    for (int u = 0; u < EDIM*EDIM; ++u) Wer[u] = We[u];
    #pragma unroll
    for (int k = 0; k < EDIM; ++k) { ber[k] = be[k]; p2r[k] = p2[k]; }

    // ---- stage ----
    {
        const float4* g4 = (const float4*)Y2; float4* s4 = (float4*)sY;
        for (int u = tid; u < NH/4; u += 256) s4[u] = g4[u];
    }
    if (tid < NN) sDv[tid] = dvg[tid];
    for (int u = tid; u < NN*EDIM; u += 256) sRm[u] = 0.f;
    __syncthreads();

    // ---- C1: R[i,m] += rc[e]*relu(ea[e,m]) for both endpoints (coalesced) ----
    for (int t = tid; t < EE; t += 256) {
        const int a = eidx[t], b = eidx[EE + t];
        const float rc = 1.f / (fmaxf(fmaxf(sDv[a], sDv[b]), 0.f) + EPSF);
        #pragma unroll
        for (int m = 0; m < EDIM; ++m) {
            const float rv = fmaxf(ea[t*EDIM + m], 0.f) * rc;
            atomicAdd(&sRm[a*EDIM + m], rv);
            atomicAdd(&sRm[b*EDIM + m], rv);
        }
    }
    __syncthreads();

    // ---- C2: S = R @ We  (116x5x5) ----
    for (int u = tid; u < NN*EDIM; u += 256) {
        const int i = u / EDIM, k = u - i*EDIM;
        float s = 0.f;
        #pragma unroll
        for (int m = 0; m < EDIM; ++m) s = fmaf(sRm[i*EDIM + m], Wer[m*EDIM + k], s);
        sS[u] = s;
    }
    __syncthreads();

    // ---- D: d2 row for the block's 4 nodes (gp recomputed from ea) ----
    {
        const int i = blockIdx.x*4 + wid;
        #pragma unroll
        for (int rep = 0; rep < 2; ++rep) {
            const int j = lane + rep*64;
            if (j < NN) {
                float val = 0.f;
                if (j != i) {
                    const int a = i < j ? i : j, b = i < j ? j : i;
                    const int e = a*NN - ((a*(a+1)) >> 1) + (b - a - 1);
                    const float da = sDv[a], db = sDv[b];
                    const float rc = 1.f / (fmaxf(fmaxf(da, db), 0.f) + EPSF);
                    float er[EDIM];
                    #pragma unroll
                    for (int m = 0; m < EDIM; ++m) er[m] = fmaxf(ea[e*EDIM + m], 0.f);
                    #pragma unroll
                    for (int k = 0; k < EDIM; ++k) {
                        float g = 0.f;
                        #pragma unroll
                        for (int m = 0; m < EDIM; ++m) g = fmaf(er[m], Wer[m*EDIM + k], g);
                        const float gp = g * rc;
                        const float v = fmaf(da, sS[a*EDIM + k] - gp,
                                       fmaf(db, sS[b*EDIM + k] - gp, ber[k]));
                        val = fmaf(fmaxf(v, 0.f), p2r[k], val);
                    }
                }
                sD2[wid*NN + j] = val;
            }
        }
    }
    __syncthreads();

    // ---- E: x3 row = D2@Y2 + b2 (diag weight already 0), partial pool ----
    {
        float acc = b2[lane];
        const float* d2r = sD2 + wid*NN;
        #pragma unroll 4
        for (int j = 0; j < NN; ++j)
            acc = fmaf(d2r[j], sY[j*HID + lane], acc);
        sR[wid*HID + lane] = acc;
    }
    __syncthreads();
    if (wid == 0) {
        float s4 = sR[lane] + sR[HID + lane] + sR[2*HID + lane] + sR[3*HID + lane];
        atomicAdd(&P[lane], s4);
    }
    __syncthreads();

    // ---- F: last block computes out = (P/N)@Wl + bl ----
    if (tid == 0) {
        __threadfence();
        int old = __hip_atomic_fetch_add(cnt, 1, __ATOMIC_ACQ_REL, __HIP_MEMORY_SCOPE_AGENT);
        sLast = (old == 28) ? 1 : 0;
    }
    __syncthreads();
    if (sLast && wid == 0) {
        const float pv = __hip_atomic_load(&P[lane], __ATOMIC_ACQUIRE, __HIP_MEMORY_SCOPE_AGENT);
        const float val = pv * (1.0f / NN);
        float res[OUTD];
        #pragma unroll
        for (int o = 0; o < OUTD; ++o) {
            float r = val * Wl[lane*OUTD + o];
            #pragma unroll
            for (int off = 32; off > 0; off >>= 1) r += __shfl_xor(r, off, 64);
            res[o] = r;
        }
        if (lane < OUTD) out[lane] = res[lane] + bl[lane];
    }
}

extern "C" void kernel_launch(void* const* d_in, const int* in_sizes, int n_in,
                              void* d_out, int out_size, void* d_ws, size_t ws_size,
                              hipStream_t stream)
{
    const float* enc   = (const float*)d_in[0];
    const float* ea    = (const float*)d_in[1];
    const int*   eidx  = (const int*)  d_in[2];
    const float* W_enc = (const float*)d_in[3];
    const float* b_enc = (const float*)d_in[4];
    const float* W1    = (const float*)d_in[5];
    const float* b1    = (const float*)d_in[6];
    const float* p1    = (const float*)d_in[7];
    const float* We    = (const float*)d_in[8];
    const float* be    = (const float*)d_in[9];
    const float* pe    = (const float*)d_in[10];
    const float* W2    = (const float*)d_in[11];
    const float* b2    = (const float*)d_in[12];
    const float* p2    = (const float*)d_in[13];
    const float* Wl    = (const float*)d_in[14];
    const float* bl    = (const float*)d_in[15];
    float* ws = (float*)d_ws;

    // Workspace (floats):
    float* Y1 = ws;                 // [NH]
    float* Y2 = ws + NH;            // [NH]
    float* d1 = ws + 2*NH;          // [EE]   (even offset: float2 staging ok)
    float* dv = d1 + EE;            // [NN]
    float* P  = dv + NN;            // [HID]
    int*  cnt = (int*)(P + HID);    // [1]
    float* out = (float*)d_out;

    kA<<<29 + (EE + 255)/256, 256, 0, stream>>>(enc, ea, W_enc, b_enc, p1, W1, Y1, d1);
    kB<<<29, 256, 0, stream>>>(d1, Y1, b1, pe, W2, dv, Y2, P, cnt);
    kCDEF<<<29, 256, 0, stream>>>(eidx, ea, dv, Y2, We, be, p2, b2, Wl, bl, P, cnt, out);
}

// Round 6
// 177.199 us; speedup vs baseline: 1.1900x; 1.1900x over previous
//
#include <hip/hip_runtime.h>

// Net_3152505995417: tiny GNN forward (N=116, E=6670, HID=64, EDIM=5).
// R7 (resubmit; R5 bench was a GPUAcquisitionTimeout, never ran).
// 3 dispatches. vs R6: kCDEF's C1 scatter rebuilt as wave-SEGMENTED
// reduction. R6's C1 (coalesced sweep + 10 LDS atomics/edge) serialized:
// edges sorted by endpoint a => all 64 lanes same a => 64-way same-address
// LDS atomic RMW x5 per edge, plus atomic-fenced loads killed pipelining.
// Now: per-wave segmented inclusive scan over a-runs (ballot head mask +
// 6 shfl_up steps per m); only segment-tail lanes atomicAdd (one per
// segment, ~2-10/wave-iter). b-side endpoints are lane-consecutive =>
// distinct addresses, plain atomicAdd kept.
//  K1 = X, Y1 (node blocks) + d1 (edge blocks)           [R0-verified code]
//  K2 = x2, dv, Y2                                       [R0-verified code]
//  K3 = R-scan/scatter -> S=R@We -> d2 (own 4 rows) -> x3 -> pool -> head
//       (last-block-finishes; threadfence + agent counter, R3/R6-verified).

#define NN   116
#define EE   6670
#define HID  64
#define EDIM 5
#define OUTD 4
#define ENC  122
#define EPSF 1e-10f
#define NH   (NN*HID)   // 7424

__device__ __forceinline__ int eid_ij(int i, int j) {
    int a = i < j ? i : j;
    int b = i < j ? j : i;
    return a*NN - ((a*(a+1)) >> 1) + (b - a - 1);   // triu k=1 row-major
}

// K1: node blocks (0..28): X row = enc@W_enc+b_enc (LDS), Y1 row = Xrow@W1.
//     edge blocks (29..55): d1 = ea@p1.
__global__ __launch_bounds__(256) void kA(
    const float* __restrict__ enc, const float* __restrict__ ea,
    const float* __restrict__ W_enc, const float* __restrict__ b_enc,
    const float* __restrict__ p1, const float* __restrict__ W1,
    float* __restrict__ Y1, float* __restrict__ d1)
{
    const int tid = threadIdx.x;
    if (blockIdx.x < 29) {
        __shared__ __align__(16) float sWe[ENC*HID];   // 31232 B
        __shared__ __align__(16) float sW1[HID*HID];   // 16384 B
        __shared__ __align__(16) float sEnc[4*ENC];    //  1952 B
        __shared__ float sX[4*HID];
        {
            const float4* g4 = (const float4*)W_enc; float4* s4 = (float4*)sWe;
            for (int u = tid; u < ENC*HID/4; u += 256) s4[u] = g4[u];
        }
        {
            const float4* g4 = (const float4*)W1; float4* s4 = (float4*)sW1;
            for (int u = tid; u < HID*HID/4; u += 256) s4[u] = g4[u];
        }
        {
            const float4* g4 = (const float4*)(enc + blockIdx.x*4*ENC); // 1952B-aligned
            float4* s4 = (float4*)sEnc;
            for (int u = tid; u < 4*ENC/4; u += 256) s4[u] = g4[u];
        }
        __syncthreads();
        const int w = tid >> 6, h = tid & 63;
        const int i = blockIdx.x*4 + w;
        float acc = b_enc[h];
        const float* er = sEnc + w*ENC;
        #pragma unroll 4
        for (int k = 0; k < ENC; ++k) acc = fmaf(er[k], sWe[k*HID + h], acc);
        sX[w*HID + h] = acc;
        __syncthreads();
        float a2 = 0.f;
        const float* xr = sX + w*HID;
        #pragma unroll 8
        for (int k = 0; k < HID; ++k) a2 = fmaf(xr[k], sW1[k*HID + h], a2);
        Y1[i*HID + h] = a2;
    } else {
        const int u = (blockIdx.x - 29)*256 + tid;
        if (u < EE) {
            const float* r = ea + u*EDIM;
            float a0 = 0.f;
            #pragma unroll
            for (int k = 0; k < EDIM; ++k) a0 = fmaf(r[k], p1[k], a0);
            d1[u] = a0;
        }
    }
}

// K2: x2 row = relu(D1@Y1 + b1); dv[i] = x2row.pe; Y2 row = x2row @ W2.
//     Block 0 also zeroes P and the completion counter for K3.
__global__ __launch_bounds__(256) void kB(
    const float* __restrict__ d1, const float* __restrict__ Y1,
    const float* __restrict__ b1, const float* __restrict__ pe,
    const float* __restrict__ W2,
    float* __restrict__ dv, float* __restrict__ Y2,
    float* __restrict__ P, int* __restrict__ cnt)
{
    __shared__ __align__(16) float sY[NH];   // 29696 B
    __shared__ __align__(16) float sD[EE];   // 26680 B
    __shared__ float sX2[4*HID];
    const int tid = threadIdx.x;
    if (blockIdx.x == 0) {
        if (tid < HID) P[tid] = 0.f;
        if (tid == 0) *cnt = 0;
    }
    {
        const float4* g4 = (const float4*)Y1; float4* s4 = (float4*)sY;
        for (int u = tid; u < NH/4; u += 256) s4[u] = g4[u];
        const float2* g2 = (const float2*)d1; float2* s2 = (float2*)sD;
        for (int u = tid; u < EE/2; u += 256) s2[u] = g2[u];
    }
    __syncthreads();
    const int w = tid >> 6, h = tid & 63;
    const int i = blockIdx.x*4 + w;
    float acc = b1[h];
    #pragma unroll 4
    for (int j = 0; j < NN; ++j) {
        int jj = (j == i) ? (j ^ 1) : j;
        float wgt = (j == i) ? 0.f : sD[eid_ij(i, jj)];
        acc = fmaf(wgt, sY[jj*HID + h], acc);
    }
    float v = fmaxf(acc, 0.f);
    float r = v * pe[h];
    #pragma unroll
    for (int off = 32; off > 0; off >>= 1) r += __shfl_down(r, off, 64);
    if (h == 0) dv[i] = r;
    sX2[w*HID + h] = v;
    __syncthreads();
    float a2 = 0.f;
    const float* xr = sX2 + w*HID;
    #pragma unroll 8
    for (int k = 0; k < HID; ++k) a2 = fmaf(xr[k], W2[k*HID + h], a2);
    Y2[i*HID + h] = a2;
}

// K3: per block (29 blocks, 4 output rows each):
//   stage Y2 + dv; R[116x5] via segmented-scan edge sweep (rc*relu(ea));
//   S = R@We in LDS; d2 for own 460 edges (gp recomputed from ea);
//   x3 rows; pool -> atomicAdd P; last block computes head.
__global__ __launch_bounds__(256) void kCDEF(
    const int* __restrict__ eidx, const float* __restrict__ ea,
    const float* __restrict__ dvg, const float* __restrict__ Y2,
    const float* __restrict__ We, const float* __restrict__ be,
    const float* __restrict__ p2, const float* __restrict__ b2,
    const float* __restrict__ Wl, const float* __restrict__ bl,
    float* __restrict__ P, int* __restrict__ cnt, float* __restrict__ out)
{
    __shared__ __align__(16) float sY[NH];     // 29696 B
    __shared__ float sRm[NN*EDIM];             // R  [116][5]
    __shared__ float sS [NN*EDIM];             // S  [116][5]
    __shared__ float sDv[NN];
    __shared__ float sD2[4*NN];
    __shared__ float sR[4*HID];
    __shared__ int sLast;
    const int tid = threadIdx.x;
    const int wid = tid >> 6, lane = tid & 63;

    // uniform small weights into registers (scalar loads)
    float Wer[EDIM*EDIM], ber[EDIM], p2r[EDIM];
    #pragma unroll
    for (int u = 0; u < EDIM*EDIM; ++u) Wer[u] = We[u];
    #pragma unroll
    for (int k = 0; k < EDIM; ++k) { ber[k] = be[k]; p2r[k] = p2[k]; }

    // ---- stage ----
    {
        const float4* g4 = (const float4*)Y2; float4* s4 = (float4*)sY;
        for (int u = tid; u < NH/4; u += 256) s4[u] = g4[u];
    }
    if (tid < NN) sDv[tid] = dvg[tid];
    for (int u = tid; u < NN*EDIM; u += 256) sRm[u] = 0.f;
    __syncthreads();

    // ---- C1: R[i,m] += rc[e]*relu(ea[e,m]) via segmented wave reduction ----
    // Edges sorted by endpoint a => a non-decreasing across lanes.
    for (int it = 0; it < (EE + 255)/256; ++it) {
        const int t = it*256 + tid;
        const bool act = (t < EE);
        const int a = act ? eidx[t]      : (NN + lane);  // distinct sentinel
        const int b = act ? eidx[EE + t] : 0;
        float rc = 0.f;
        if (act) rc = 1.f / (fmaxf(fmaxf(sDv[a], sDv[b]), 0.f) + EPSF);
        float rv0[EDIM];
        #pragma unroll
        for (int m = 0; m < EDIM; ++m)
            rv0[m] = act ? fmaxf(ea[t*EDIM + m], 0.f) * rc : 0.f;

        // segment geometry within the wave
        const int aprev = __shfl_up(a, 1, 64);
        const bool head = (lane == 0) || (a != aprev);
        const unsigned long long mask = __ballot(head);
        const unsigned long long below =
            mask & ((lane == 63) ? ~0ULL : ((2ULL << lane) - 1ULL));
        const int hd  = 63 - __clzll(below);   // my segment head lane
        const int lim = lane - hd;             // add shfl_up(d) iff d <= lim
        const int anext = __shfl_down(a, 1, 64);
        const bool tail = (lane == 63) || (a != anext);

        // segmented inclusive scan per m; tails hold segment totals
        float sc[EDIM];
        #pragma unroll
        for (int m = 0; m < EDIM; ++m) {
            float v = rv0[m];
            #pragma unroll
            for (int d = 1; d < 64; d <<= 1) {
                const float vv = __shfl_up(v, d, 64);
                v += (d <= lim) ? vv : 0.f;
            }
            sc[m] = v;
        }
        if (tail && a < NN) {
            #pragma unroll
            for (int m = 0; m < EDIM; ++m) atomicAdd(&sRm[a*EDIM + m], sc[m]);
        }
        if (act) {
            #pragma unroll
            for (int m = 0; m < EDIM; ++m) atomicAdd(&sRm[b*EDIM + m], rv0[m]);
        }
    }
    __syncthreads();

    // ---- C2: S = R @ We  (116x5x5) ----
    for (int u = tid; u < NN*EDIM; u += 256) {
        const int i = u / EDIM, k = u - i*EDIM;
        float s = 0.f;
        #pragma unroll
        for (int m = 0; m < EDIM; ++m) s = fmaf(sRm[i*EDIM + m], Wer[m*EDIM + k], s);
        sS[u] = s;
    }
    __syncthreads();

    // ---- D: d2 row for the block's 4 nodes (gp recomputed from ea) ----
    {
        const int i = blockIdx.x*4 + wid;
        #pragma unroll
        for (int rep = 0; rep < 2; ++rep) {
            const int j = lane + rep*64;
            if (j < NN) {
                float val = 0.f;
                if (j != i) {
                    const int a = i < j ? i : j, b = i < j ? j : i;
                    const int e = a*NN - ((a*(a+1)) >> 1) + (b - a - 1);
                    const float da = sDv[a], db = sDv[b];
                    const float rc = 1.f / (fmaxf(fmaxf(da, db), 0.f) + EPSF);
                    float er[EDIM];
                    #pragma unroll
                    for (int m = 0; m < EDIM; ++m) er[m] = fmaxf(ea[e*EDIM + m], 0.f);
                    #pragma unroll
                    for (int k = 0; k < EDIM; ++k) {
                        float g = 0.f;
                        #pragma unroll
                        for (int m = 0; m < EDIM; ++m) g = fmaf(er[m], Wer[m*EDIM + k], g);
                        const float gp = g * rc;
                        const float v = fmaf(da, sS[a*EDIM + k] - gp,
                                       fmaf(db, sS[b*EDIM + k] - gp, ber[k]));
                        val = fmaf(fmaxf(v, 0.f), p2r[k], val);
                    }
                }
                sD2[wid*NN + j] = val;
            }
        }
    }
    __syncthreads();

    // ---- E: x3 row = D2@Y2 + b2 (diag weight already 0), partial pool ----
    {
        float acc = b2[lane];
        const float* d2r = sD2 + wid*NN;
        #pragma unroll 4
        for (int j = 0; j < NN; ++j)
            acc = fmaf(d2r[j], sY[j*HID + lane], acc);
        sR[wid*HID + lane] = acc;
    }
    __syncthreads();
    if (wid == 0) {
        float s4 = sR[lane] + sR[HID + lane] + sR[2*HID + lane] + sR[3*HID + lane];
        atomicAdd(&P[lane], s4);
    }
    __syncthreads();

    // ---- F: last block computes out = (P/N)@Wl + bl ----
    if (tid == 0) {
        __threadfence();
        int old = __hip_atomic_fetch_add(cnt, 1, __ATOMIC_ACQ_REL, __HIP_MEMORY_SCOPE_AGENT);
        sLast = (old == 28) ? 1 : 0;
    }
    __syncthreads();
    if (sLast && wid == 0) {
        const float pv = __hip_atomic_load(&P[lane], __ATOMIC_ACQUIRE, __HIP_MEMORY_SCOPE_AGENT);
        const float val = pv * (1.0f / NN);
        float res[OUTD];
        #pragma unroll
        for (int o = 0; o < OUTD; ++o) {
            float r = val * Wl[lane*OUTD + o];
            #pragma unroll
            for (int off = 32; off > 0; off >>= 1) r += __shfl_xor(r, off, 64);
            res[o] = r;
        }
        if (lane < OUTD) out[lane] = res[lane] + bl[lane];
    }
}

extern "C" void kernel_launch(void* const* d_in, const int* in_sizes, int n_in,
                              void* d_out, int out_size, void* d_ws, size_t ws_size,
                              hipStream_t stream)
{
    const float* enc   = (const float*)d_in[0];
    const float* ea    = (const float*)d_in[1];
    const int*   eidx  = (const int*)  d_in[2];
    const float* W_enc = (const float*)d_in[3];
    const float* b_enc = (const float*)d_in[4];
    const float* W1    = (const float*)d_in[5];
    const float* b1    = (const float*)d_in[6];
    const float* p1    = (const float*)d_in[7];
    const float* We    = (const float*)d_in[8];
    const float* be    = (const float*)d_in[9];
    const float* pe    = (const float*)d_in[10];
    const float* W2    = (const float*)d_in[11];
    const float* b2    = (const float*)d_in[12];
    const float* p2    = (const float*)d_in[13];
    const float* Wl    = (const float*)d_in[14];
    const float* bl    = (const float*)d_in[15];
    float* ws = (float*)d_ws;

    // Workspace (floats):
    float* Y1 = ws;                 // [NH]
    float* Y2 = ws + NH;            // [NH]
    float* d1 = ws + 2*NH;          // [EE]   (even offset: float2 staging ok)
    float* dv = d1 + EE;            // [NN]
    float* P  = dv + NN;            // [HID]
    int*  cnt = (int*)(P + HID);    // [1]
    float* out = (float*)d_out;

    kA<<<29 + (EE + 255)/256, 256, 0, stream>>>(enc, ea, W_enc, b_enc, p1, W1, Y1, d1);
    kB<<<29, 256, 0, stream>>>(d1, Y1, b1, pe, W2, dv, Y2, P, cnt);
    kCDEF<<<29, 256, 0, stream>>>(eidx, ea, dv, Y2, We, be, p2, b2, Wl, bl, P, cnt, out);
}

// Round 7
// 116.697 us; speedup vs baseline: 1.8069x; 1.5184x over previous
//
#include <hip/hip_runtime.h>

// Net_3152505995417: tiny GNN forward (N=116, E=6670, HID=64, EDIM=5).
// R8: back to R0's PARTITIONED structure (R0=126us beat all fused variants;
// boundary cost is ~5us, not ~20 -- fused kCDEF's 29x-redundant edge sweep
// was the real regression). 4 dispatches:
//  kA = X, Y1 (node blocks) + d1, G (edge blocks)   [R0-verified verbatim]
//  kB = x2, dv, Y2 (+ zero P, cnt)                  [R0-verified verbatim]
//  kC = S[i,k] gather (one wave per (i,k))          [R0-verified verbatim]
//  kDEF = per-block OWN-4-ROWS d2 (460 edges, no redundancy) -> x3 -> pool
//         -> last-block head (fence+agent counter, R3/R6/R7-verified).
// vs R0: kD and kF folded into kE (saves 2 kernels + 2 boundaries).

#define NN   116
#define EE   6670
#define HID  64
#define EDIM 5
#define OUTD 4
#define ENC  122
#define EPSF 1e-10f
#define NH   (NN*HID)   // 7424

__device__ __forceinline__ int eid_ij(int i, int j) {
    int a = i < j ? i : j;
    int b = i < j ? j : i;
    return a*NN - ((a*(a+1)) >> 1) + (b - a - 1);   // triu k=1 row-major
}

// kA: node blocks (0..28): X row = enc@W_enc+b_enc (LDS), Y1 row = Xrow@W1.
//     edge blocks (29..): d1 = ea@p1 ; G = relu(ea)@We.
__global__ __launch_bounds__(256) void kA(
    const float* __restrict__ enc, const float* __restrict__ ea,
    const float* __restrict__ W_enc, const float* __restrict__ b_enc,
    const float* __restrict__ p1, const float* __restrict__ We,
    const float* __restrict__ W1,
    float* __restrict__ Y1, float* __restrict__ d1, float* __restrict__ G)
{
    const int tid = threadIdx.x;
    if (blockIdx.x < 29) {
        __shared__ __align__(16) float sWe[ENC*HID];   // 31232 B
        __shared__ __align__(16) float sW1[HID*HID];   // 16384 B
        __shared__ __align__(16) float sEnc[4*ENC];    //  1952 B
        __shared__ float sX[4*HID];
        {
            const float4* g4 = (const float4*)W_enc; float4* s4 = (float4*)sWe;
            for (int u = tid; u < ENC*HID/4; u += 256) s4[u] = g4[u];
        }
        {
            const float4* g4 = (const float4*)W1; float4* s4 = (float4*)sW1;
            for (int u = tid; u < HID*HID/4; u += 256) s4[u] = g4[u];
        }
        {
            const float4* g4 = (const float4*)(enc + blockIdx.x*4*ENC); // 1952B-aligned
            float4* s4 = (float4*)sEnc;
            for (int u = tid; u < 4*ENC/4; u += 256) s4[u] = g4[u];
        }
        __syncthreads();
        const int w = tid >> 6, h = tid & 63;
        const int i = blockIdx.x*4 + w;
        float acc = b_enc[h];
        const float* er = sEnc + w*ENC;
        #pragma unroll 4
        for (int k = 0; k < ENC; ++k) acc = fmaf(er[k], sWe[k*HID + h], acc);
        sX[w*HID + h] = acc;
        __syncthreads();
        float a2 = 0.f;
        const float* xr = sX + w*HID;
        #pragma unroll 8
        for (int k = 0; k < HID; ++k) a2 = fmaf(xr[k], sW1[k*HID + h], a2);
        Y1[i*HID + h] = a2;
    } else {
        int u = (blockIdx.x - 29)*256 + tid;
        if (u < EE) {
            const float* r = ea + u*EDIM;
            float a0 = 0.f;
            #pragma unroll
            for (int k = 0; k < EDIM; ++k) a0 = fmaf(r[k], p1[k], a0);
            d1[u] = a0;
        } else if (u < EE + EE*EDIM) {
            int idx = u - EE;
            int e = idx / EDIM, k = idx - e*EDIM;
            const float* r = ea + e*EDIM;
            float a0 = 0.f;
            #pragma unroll
            for (int m = 0; m < EDIM; ++m) a0 = fmaf(fmaxf(r[m], 0.f), We[m*EDIM + k], a0);
            G[idx] = a0;
        }
    }
}

// kB: x2 row = relu(D1@Y1 + b1); dv[i] = x2row.pe; Y2 row = x2row @ W2.
//     Block 0 also zeroes P and the completion counter.
__global__ __launch_bounds__(256) void kB(
    const float* __restrict__ d1, const float* __restrict__ Y1,
    const float* __restrict__ b1, const float* __restrict__ pe,
    const float* __restrict__ W2,
    float* __restrict__ dv, float* __restrict__ Y2,
    float* __restrict__ P, int* __restrict__ cnt)
{
    __shared__ __align__(16) float sY[NH];   // 29696 B
    __shared__ __align__(16) float sD[EE];   // 26680 B
    __shared__ float sX2[4*HID];
    const int tid = threadIdx.x;
    if (blockIdx.x == 0) {
        if (tid < HID) P[tid] = 0.f;
        if (tid == 0) *cnt = 0;
    }
    {
        const float4* g4 = (const float4*)Y1; float4* s4 = (float4*)sY;
        for (int u = tid; u < NH/4; u += 256) s4[u] = g4[u];
        const float2* g2 = (const float2*)d1; float2* s2 = (float2*)sD;
        for (int u = tid; u < EE/2; u += 256) s2[u] = g2[u];
    }
    __syncthreads();
    const int w = tid >> 6, h = tid & 63;
    const int i = blockIdx.x*4 + w;
    float acc = b1[h];
    #pragma unroll 4
    for (int j = 0; j < NN; ++j) {
        int jj = (j == i) ? (j ^ 1) : j;
        float wgt = (j == i) ? 0.f : sD[eid_ij(i, jj)];
        acc = fmaf(wgt, sY[jj*HID + h], acc);
    }
    float v = fmaxf(acc, 0.f);
    float r = v * pe[h];
    #pragma unroll
    for (int off = 32; off > 0; off >>= 1) r += __shfl_down(r, off, 64);
    if (h == 0) dv[i] = r;
    sX2[w*HID + h] = v;
    __syncthreads();
    float a2 = 0.f;
    const float* xr = sX2 + w*HID;
    #pragma unroll 8
    for (int k = 0; k < HID; ++k) a2 = fmaf(xr[k], W2[k*HID + h], a2);
    Y2[i*HID + h] = a2;
}

// kC: S[i,k] = sum_{j!=i} G[eid(i,j),k] / (max(dv[i],dv[j],0)+eps)
//     one wave per (i,k): 580 waves = 145 blocks x 256. Lanes split j.
__global__ __launch_bounds__(256) void kC(
    const float* __restrict__ G, const float* __restrict__ dv,
    float* __restrict__ S)
{
    const int wg = blockIdx.x*4 + (threadIdx.x >> 6);   // 0..579
    const int lane = threadIdx.x & 63;
    const int i = wg / EDIM, k = wg - i*EDIM;
    const float di = dv[i];
    float acc = 0.f;
    #pragma unroll
    for (int rep = 0; rep < 2; ++rep) {
        int j = lane + rep*64;
        if (j < NN && j != i) {
            float cm = fmaxf(fmaxf(di, dv[j]), 0.f) + EPSF;
            acc += G[eid_ij(i, j)*EDIM + k] / cm;
        }
    }
    #pragma unroll
    for (int off = 32; off > 0; off >>= 1) acc += __shfl_down(acc, off, 64);
    if (lane == 0) S[wg] = acc;
}

// kDEF: per block (29 blocks, 4 output rows each):
//   stage Y2 + S + dv; d2 for OWN 4 rows only (460 edges, G loaded);
//   x3 rows; pool -> atomicAdd P; last block computes head.
__global__ __launch_bounds__(256) void kDEF(
    const float* __restrict__ G, const float* __restrict__ dvg,
    const float* __restrict__ Sg, const float* __restrict__ Y2,
    const float* __restrict__ be, const float* __restrict__ p2,
    const float* __restrict__ b2, const float* __restrict__ Wl,
    const float* __restrict__ bl,
    float* __restrict__ P, int* __restrict__ cnt, float* __restrict__ out)
{
    __shared__ __align__(16) float sY[NH];     // 29696 B
    __shared__ float sS[NN*EDIM];              // 2320 B
    __shared__ float sDv[NN];
    __shared__ float sD2[4*NN];
    __shared__ float sR[4*HID];
    __shared__ int sLast;
    const int tid = threadIdx.x;
    const int wid = tid >> 6, lane = tid & 63;

    float ber[EDIM], p2r[EDIM];
    #pragma unroll
    for (int k = 0; k < EDIM; ++k) { ber[k] = be[k]; p2r[k] = p2[k]; }

    // ---- stage ----
    {
        const float4* g4 = (const float4*)Y2; float4* s4 = (float4*)sY;
        for (int u = tid; u < NH/4; u += 256) s4[u] = g4[u];
    }
    for (int u = tid; u < NN*EDIM; u += 256) sS[u] = Sg[u];
    if (tid < NN) sDv[tid] = dvg[tid];
    __syncthreads();

    // ---- D: d2 for the block's own 4 rows (460 edges) ----
    {
        const int i = blockIdx.x*4 + wid;
        #pragma unroll
        for (int rep = 0; rep < 2; ++rep) {
            const int j = lane + rep*64;
            if (j < NN) {
                float val = 0.f;
                if (j != i) {
                    const int a = i < j ? i : j, b = i < j ? j : i;
                    const int e = a*NN - ((a*(a+1)) >> 1) + (b - a - 1);
                    const float da = sDv[a], db = sDv[b];
                    const float rc = 1.f / (fmaxf(fmaxf(da, db), 0.f) + EPSF);
                    #pragma unroll
                    for (int k = 0; k < EDIM; ++k) {
                        const float gp = G[e*EDIM + k] * rc;
                        const float v = fmaf(da, sS[a*EDIM + k] - gp,
                                       fmaf(db, sS[b*EDIM + k] - gp, ber[k]));
                        val = fmaf(fmaxf(v, 0.f), p2r[k], val);
                    }
                }
                sD2[wid*NN + j] = val;
            }
        }
    }
    __syncthreads();

    // ---- E: x3 row = D2@Y2 + b2 (diag weight already 0), partial pool ----
    {
        float acc = b2[lane];
        const float* d2r = sD2 + wid*NN;
        #pragma unroll 4
        for (int j = 0; j < NN; ++j)
            acc = fmaf(d2r[j], sY[j*HID + lane], acc);
        sR[wid*HID + lane] = acc;
    }
    __syncthreads();
    if (wid == 0) {
        float s4 = sR[lane] + sR[HID + lane] + sR[2*HID + lane] + sR[3*HID + lane];
        atomicAdd(&P[lane], s4);
    }
    __syncthreads();

    // ---- F: last block computes out = (P/N)@Wl + bl ----
    if (tid == 0) {
        __threadfence();
        int old = __hip_atomic_fetch_add(cnt, 1, __ATOMIC_ACQ_REL, __HIP_MEMORY_SCOPE_AGENT);
        sLast = (old == 28) ? 1 : 0;
    }
    __syncthreads();
    if (sLast && wid == 0) {
        const float pv = __hip_atomic_load(&P[lane], __ATOMIC_ACQUIRE, __HIP_MEMORY_SCOPE_AGENT);
        const float val = pv * (1.0f / NN);
        float res[OUTD];
        #pragma unroll
        for (int o = 0; o < OUTD; ++o) {
            float r = val * Wl[lane*OUTD + o];
            #pragma unroll
            for (int off = 32; off > 0; off >>= 1) r += __shfl_xor(r, off, 64);
            res[o] = r;
        }
        if (lane < OUTD) out[lane] = res[lane] + bl[lane];
    }
}

extern "C" void kernel_launch(void* const* d_in, const int* in_sizes, int n_in,
                              void* d_out, int out_size, void* d_ws, size_t ws_size,
                              hipStream_t stream)
{
    const float* enc   = (const float*)d_in[0];
    const float* ea    = (const float*)d_in[1];
    const float* W_enc = (const float*)d_in[3];
    const float* b_enc = (const float*)d_in[4];
    const float* W1    = (const float*)d_in[5];
    const float* b1    = (const float*)d_in[6];
    const float* p1    = (const float*)d_in[7];
    const float* We    = (const float*)d_in[8];
    const float* be    = (const float*)d_in[9];
    const float* pe    = (const float*)d_in[10];
    const float* W2    = (const float*)d_in[11];
    const float* b2    = (const float*)d_in[12];
    const float* p2    = (const float*)d_in[13];
    const float* Wl    = (const float*)d_in[14];
    const float* bl    = (const float*)d_in[15];
    float* ws = (float*)d_ws;

    // Workspace (floats):
    float* Y1 = ws;                 // [NH]
    float* Y2 = ws + NH;            // [NH]
    float* d1 = ws + 2*NH;          // [EE]   (even offset: float2 staging ok)
    float* G  = d1 + EE;            // [EE*EDIM]
    float* dv = G + EE*EDIM;        // [NN]
    float* S  = dv + NN;            // [NN*EDIM]
    float* P  = S + NN*EDIM;        // [HID]
    int*  cnt = (int*)(P + HID);    // [1]
    float* out = (float*)d_out;

    kA<<<29 + (EE + EE*EDIM + 255)/256, 256, 0, stream>>>(enc, ea, W_enc, b_enc, p1, We, W1, Y1, d1, G);
    kB<<<29, 256, 0, stream>>>(d1, Y1, b1, pe, W2, dv, Y2, P, cnt);
    kC<<<(NN*EDIM)/4, 256, 0, stream>>>(G, dv, S);
    kDEF<<<29, 256, 0, stream>>>(G, dv, S, Y2, be, p2, b2, Wl, bl, P, cnt, out);
}